// Round 6
// baseline (178.376 us; speedup 1.0000x reference)
//
#include <hip/hip_runtime.h>
#include <hip/hip_fp16.h>

#define DIM   160
#define DIM2  25600
#define TY    32
#define TX    32
#define TZ    20
#define HY    38            // TY + 6
#define HX    38            // TX + 6
#define SSTR  42            // staging row stride in float2 (bank-verified)
#define YSTR  36            // yc row stride in floats (bank-verified)
#define YCH   (HY * YSTR)   // 1368 floats per channel
#define NSL   26            // TZ + 6
#define NSITE (HY * HX)     // 1444
#define NVOX_D 16384000.0

#define W0 0.03663285f
#define W1 0.11128076f
#define W2 0.21674532f
#define W3 0.27068213f

__global__ void ssim_zero_acc(double* acc) {
    if (threadIdx.x == 0 && blockIdx.x == 0) acc[0] = 0.0;
}

__global__ __launch_bounds__(256, 3) void ssim_main(const float* __restrict__ P,
                                                    const float* __restrict__ T,
                                                    double* __restrict__ acc) {
    const float Wk[7] = {W0, W1, W2, W3, W2, W1, W0};

    __shared__ float2 sPT[HY * SSTR];      // raw (p,t), single-buffered
    __shared__ float  yc[5 * YCH];         // x-convolved channels
    __shared__ float  red[4];

    const int tid = threadIdx.x;
    int bid = blockIdx.x;
    int b  = bid / 200;  int r  = bid - b * 200;   // 8 zc * 5 ty * 5 tx
    int zc = r / 25;     int r2 = r - zc * 25;
    int ty = r2 / 5;     int tx = r2 - ty * 5;

    const int base = b * (DIM * DIM * DIM);
    const int z0 = zc * TZ, y0 = ty * TY - 3, x0 = tx * TX - 3;

    // ---- hoisted staging sites: s = tid + 256k, k<6 (1444 = 5*256 + 164) ----
    int  gofs[6], wofs[6];
    bool ld[6], st[6];
#pragma unroll
    for (int k = 0; k < 6; ++k) {
        int s = tid + 256 * k;
        st[k] = (s < NSITE);
        int y = s / HX, x = s - y * HX;
        int gy = y0 + y, gx = x0 + x;
        ld[k] = st[k] & ((unsigned)gy < (unsigned)DIM) & ((unsigned)gx < (unsigned)DIM);
        gofs[k] = gy * DIM + gx;
        wofs[k] = y * SSTR + x;
    }

    // ---- x-conv task ids: t1 = tid; t2 = 256 + 12*(wave) + lane, lane<12 ----
    const int t2 = 256 + (tid >> 6) * 12 + (tid & 63);
    const bool has2 = ((tid & 63) < 12);

    // ---- y-conv read base: yout = tid>>3 (32 rows), xq = tid&7 ----
    const float* ybase = &yc[(tid >> 3) * YSTR + (tid & 7) * 4];

    const __half2 hz = __float2half2_rn(0.f);
    __half2 azA[5][7], azB[5][7];
#pragma unroll
    for (int c = 0; c < 5; ++c)
#pragma unroll
        for (int j = 0; j < 7; ++j) { azA[c][j] = hz; azB[c][j] = hz; }

    float lsum = 0.f;

    auto xtask = [&](int t) {
        int row = t >> 3, xq = t & 7;
        const float4* src = (const float4*)(sPT + row * SSTR + 4 * xq);
        float4 q0 = src[0], q1 = src[1], q2 = src[2], q3 = src[3], q4 = src[4];
        float pa[10] = {q0.x, q0.z, q1.x, q1.z, q2.x, q2.z, q3.x, q3.z, q4.x, q4.z};
        float ta[10] = {q0.y, q0.w, q1.y, q1.w, q2.y, q2.w, q3.y, q3.w, q4.y, q4.w};
        float sacc[5][4];
#pragma unroll
        for (int c = 0; c < 5; ++c)
#pragma unroll
            for (int o = 0; o < 4; ++o) sacc[c][o] = 0.f;
#pragma unroll
        for (int j = 0; j < 10; ++j) {
            float p = pa[j], t = ta[j];
            float p2 = p * p, tt = t * t, pt = p * t;
#pragma unroll
            for (int o = 0; o < 4; ++o) {
                int k = j - o;
                if (k >= 0 && k < 7) {
                    float w = Wk[k];
                    sacc[0][o] = fmaf(w, p,  sacc[0][o]);
                    sacc[1][o] = fmaf(w, t,  sacc[1][o]);
                    sacc[2][o] = fmaf(w, p2, sacc[2][o]);
                    sacc[3][o] = fmaf(w, tt, sacc[3][o]);
                    sacc[4][o] = fmaf(w, pt, sacc[4][o]);
                }
            }
        }
        int wb = row * YSTR + 4 * xq;
#pragma unroll
        for (int c = 0; c < 5; ++c)
            *(float4*)&yc[c * YCH + wb] =
                make_float4(sacc[c][0], sacc[c][1], sacc[c][2], sacc[c][3]);
    };

    // ---- prologue: stage slice zs = z0-3 ----
    {
        int zs = z0 - 3;
        bool zok = (unsigned)zs < (unsigned)DIM;
        const float* Pp = P + base + zs * DIM2;
        const float* Tp = T + base + zs * DIM2;
        float rp[6], rt[6];
#pragma unroll
        for (int k = 0; k < 6; ++k) {
            rp[k] = 0.f; rt[k] = 0.f;
            if (zok && ld[k]) { rp[k] = Pp[gofs[k]]; rt[k] = Tp[gofs[k]]; }
        }
#pragma unroll
        for (int k = 0; k < 6; ++k)
            if (st[k]) sPT[wofs[k]] = make_float2(rp[k], rt[k]);
    }
    __syncthreads();

    for (int i = 0; i < NSL; ++i) {
        // ---- phase A: x-conv (reads sPT, writes yc) ----
        xtask(tid);
        if (has2) xtask(t2);
        __syncthreads();

        // ---- phase B: prefetch next slice, y-conv+z+SSIM, commit stage ----
        const bool hn = (i + 1 < NSL);
        float rp[6], rt[6];
        if (hn) {
            int zs = z0 + i - 2;
            bool zok = (unsigned)zs < (unsigned)DIM;
            const float* Pp = P + base + zs * DIM2;
            const float* Tp = T + base + zs * DIM2;
#pragma unroll
            for (int k = 0; k < 6; ++k) {
                rp[k] = 0.f; rt[k] = 0.f;
                if (zok && ld[k]) { rp[k] = Pp[gofs[k]]; rt[k] = Tp[gofs[k]]; }
            }
        }

        // y-conv: 35 b128, single base + immediate offsets
        float sy[5][4];
#pragma unroll
        for (int c = 0; c < 5; ++c)
#pragma unroll
            for (int o = 0; o < 4; ++o) sy[c][o] = 0.f;
#pragma unroll
        for (int c = 0; c < 5; ++c) {
#pragma unroll
            for (int k = 0; k < 7; ++k) {
                float4 v = *(const float4*)&ybase[c * YCH + k * YSTR];
                float w = Wk[k];
                sy[c][0] = fmaf(w, v.x, sy[c][0]);
                sy[c][1] = fmaf(w, v.y, sy[c][1]);
                sy[c][2] = fmaf(w, v.z, sy[c][2]);
                sy[c][3] = fmaf(w, v.w, sy[c][3]);
            }
        }

        // z scatter into two half2 pipes
#pragma unroll
        for (int c = 0; c < 5; ++c) {
            __half2 a2 = __floats2half2_rn(sy[c][0], sy[c][1]);
            __half2 b2 = __floats2half2_rn(sy[c][2], sy[c][3]);
#pragma unroll
            for (int j = 0; j < 7; ++j) {
                __half2 w2 = __float2half2_rn(Wk[6 - j]);
                azA[c][j] = __hfma2(w2, a2, azA[c][j]);
                azB[c][j] = __hfma2(w2, b2, azB[c][j]);
            }
        }

        if (i >= 6) {
#pragma unroll
            for (int pipe = 0; pipe < 2; ++pipe) {
                __half2 h0 = pipe ? azB[0][0] : azA[0][0];
                __half2 h1 = pipe ? azB[1][0] : azA[1][0];
                __half2 h2 = pipe ? azB[2][0] : azA[2][0];
                __half2 h3 = pipe ? azB[3][0] : azA[3][0];
                __half2 h4 = pipe ? azB[4][0] : azA[4][0];
                {
                    float mp = __low2float(h0), mt = __low2float(h1);
                    float ep2 = __low2float(h2), et2 = __low2float(h3), ept = __low2float(h4);
                    float mp2 = mp * mp, mt2 = mt * mt, mpt = mp * mt;
                    float num = fmaf(2.f, mpt, 1e-4f) * fmaf(2.f, ept - mpt, 9e-4f);
                    float den = (mp2 + mt2 + 1e-4f) * ((ep2 - mp2) + (et2 - mt2) + 9e-4f);
                    lsum += num * __builtin_amdgcn_rcpf(den);
                }
                {
                    float mp = __high2float(h0), mt = __high2float(h1);
                    float ep2 = __high2float(h2), et2 = __high2float(h3), ept = __high2float(h4);
                    float mp2 = mp * mp, mt2 = mt * mt, mpt = mp * mt;
                    float num = fmaf(2.f, mpt, 1e-4f) * fmaf(2.f, ept - mpt, 9e-4f);
                    float den = (mp2 + mt2 + 1e-4f) * ((ep2 - mp2) + (et2 - mt2) + 9e-4f);
                    lsum += num * __builtin_amdgcn_rcpf(den);
                }
            }
        }

        // shift z pipes
#pragma unroll
        for (int c = 0; c < 5; ++c) {
#pragma unroll
            for (int j = 0; j < 6; ++j) { azA[c][j] = azA[c][j + 1]; azB[c][j] = azB[c][j + 1]; }
            azA[c][6] = hz; azB[c][6] = hz;
        }

        // commit next slice into sPT
        if (hn) {
#pragma unroll
            for (int k = 0; k < 6; ++k)
                if (st[k]) sPT[wofs[k]] = make_float2(rp[k], rt[k]);
        }
        __syncthreads();
    }

    // ---- block reduction, one f64 atomic ----
#pragma unroll
    for (int off = 32; off > 0; off >>= 1) lsum += __shfl_down(lsum, off);
    if ((tid & 63) == 0) red[tid >> 6] = lsum;
    __syncthreads();
    if (tid == 0) atomicAdd(acc, (double)(red[0] + red[1] + red[2] + red[3]));
}

__global__ void ssim_finalize(const double* __restrict__ acc, float* __restrict__ out) {
    if (threadIdx.x == 0 && blockIdx.x == 0)
        out[0] = 1.f - (float)(acc[0] / NVOX_D);
}

extern "C" void kernel_launch(void* const* d_in, const int* in_sizes, int n_in,
                              void* d_out, int out_size, void* d_ws, size_t ws_size,
                              hipStream_t stream) {
    const float* P = (const float*)d_in[0];
    const float* T = (const float*)d_in[1];
    float* out = (float*)d_out;
    double* acc = (double*)d_ws;

    ssim_zero_acc<<<1, 64, 0, stream>>>(acc);
    ssim_main<<<4 * 8 * 5 * 5, 256, 0, stream>>>(P, T, acc);
    ssim_finalize<<<1, 64, 0, stream>>>(acc, out);
}

// Round 7
// 156.359 us; speedup vs baseline: 1.1408x; 1.1408x over previous
//
#include <hip/hip_runtime.h>
#include <hip/hip_fp16.h>

#define DIM   160
#define DIM2  25600
#define TY    32
#define TX    32
#define TZ    20
#define HY    38            // TY + 6
#define HX    38            // TX + 6
#define NSL   26            // TZ + 6
#define NSITE (HY * HX)     // 1444
#define YSTR  39            // yc row stride (odd -> verified bank-uniform)
#define YCH   (TY * YSTR)   // 1248 floats per channel
#define NVOX_D 16384000.0

#define W0 0.03663285f
#define W1 0.11128076f
#define W2 0.21674532f
#define W3 0.27068213f

__global__ void ssim_zero_acc(double* acc) {
    if (threadIdx.x == 0 && blockIdx.x == 0) acc[0] = 0.0;
}

__global__ __launch_bounds__(256, 3) void ssim_main(const float* __restrict__ P,
                                                    const float* __restrict__ T,
                                                    double* __restrict__ acc) {
    const float Wk[7] = {W0, W1, W2, W3, W2, W1, W0};

    __shared__ float2 sPT[NSITE];       // raw (p,t) interleaved, single buffer
    __shared__ float  yc[5 * YCH];      // y-convolved channels, stride 39
    __shared__ float  red[4];

    const int tid = threadIdx.x;
    int bid = blockIdx.x;
    int b  = bid / 200;  int r  = bid - b * 200;   // 8 zc * 5 ty * 5 tx
    int zc = r / 25;     int r2 = r - zc * 25;
    int ty = r2 / 5;     int tx = r2 - ty * 5;

    const int base = b * (DIM * DIM * DIM);
    const int z0 = zc * TZ, y0 = ty * TY - 3, x0 = tx * TX - 3;

    // ---- hoisted staging sites: u = tid + 256k, k<6 (1444 = 5*256 + 164) ----
    int  gofs[6];
    bool ld[6], st[6];
#pragma unroll
    for (int k = 0; k < 6; ++k) {
        int u = tid + 256 * k;
        st[k] = (u < NSITE);
        int y = u / HX, x = u - y * HX;
        int gy = y0 + y, gx = x0 + x;
        ld[k] = st[k] & ((unsigned)gy < (unsigned)DIM) & ((unsigned)gx < (unsigned)DIM);
        gofs[k] = gy * DIM + gx;
    }

    // ---- y-conv quad-task mapping: t -> col x = t>>3, row-quad g = t&7 ----
    // ---- x-conv: row cy = tid>>3 (32 rows), quad jq = tid&7 ----
    const int xrd = (tid >> 3) * YSTR + 4 * (tid & 7);

    const __half2 hz = __float2half2_rn(0.f);
    __half2 azA[5][7], azB[5][7];
#pragma unroll
    for (int c = 0; c < 5; ++c)
#pragma unroll
        for (int j = 0; j < 7; ++j) { azA[c][j] = hz; azB[c][j] = hz; }

    float lsum = 0.f;

    // y-conv quad: rows 4g..4g+3 at col x, taps 4g..4g+9
    auto ytask = [&](int x, int g) {
        const float2* s = sPT + (4 * g) * HX + x;
        float ya[5][4];
#pragma unroll
        for (int c = 0; c < 5; ++c)
#pragma unroll
            for (int j = 0; j < 4; ++j) ya[c][j] = 0.f;
#pragma unroll
        for (int k = 0; k < 10; ++k) {
            float2 v = s[k * HX];
            float p = v.x, t = v.y;
            float p2 = p * p, t2 = t * t, pt = p * t;
#pragma unroll
            for (int j = 0; j < 4; ++j) {
                int kk = k - j;
                if (kk >= 0 && kk < 7) {
                    float w = Wk[kk];
                    ya[0][j] = fmaf(w, p,  ya[0][j]);
                    ya[1][j] = fmaf(w, t,  ya[1][j]);
                    ya[2][j] = fmaf(w, p2, ya[2][j]);
                    ya[3][j] = fmaf(w, t2, ya[3][j]);
                    ya[4][j] = fmaf(w, pt, ya[4][j]);
                }
            }
        }
#pragma unroll
        for (int c = 0; c < 5; ++c)
#pragma unroll
            for (int j = 0; j < 4; ++j)
                yc[c * YCH + (4 * g + j) * YSTR + x] = ya[c][j];
    };

    // ---- prologue: stage slice zs = z0-3 ----
    {
        int zs = z0 - 3;
        bool zok = (unsigned)zs < (unsigned)DIM;
        const float* Pp = P + base + zs * DIM2;
        const float* Tp = T + base + zs * DIM2;
        float rp[6], rt[6];
#pragma unroll
        for (int k = 0; k < 6; ++k) {
            rp[k] = 0.f; rt[k] = 0.f;
            if (zok && ld[k]) { rp[k] = Pp[gofs[k]]; rt[k] = Tp[gofs[k]]; }
        }
#pragma unroll
        for (int k = 0; k < 6; ++k)
            if (st[k]) sPT[tid + 256 * k] = make_float2(rp[k], rt[k]);
    }
    __syncthreads();

    for (int i = 0; i < NSL; ++i) {
        const bool hn = (i + 1 < NSL);
        float rp[6], rt[6];

        // ---- prefetch next slice into regs (hides HBM under y-conv) ----
        if (hn) {
            int zs = z0 + i - 2;
            bool zok = (unsigned)zs < (unsigned)DIM;
            const float* Pp = P + base + zs * DIM2;
            const float* Tp = T + base + zs * DIM2;
#pragma unroll
            for (int k = 0; k < 6; ++k) {
                rp[k] = 0.f; rt[k] = 0.f;
                if (zok && ld[k]) { rp[k] = Pp[gofs[k]]; rt[k] = Tp[gofs[k]]; }
            }
        }

        // ---- phase A: y-conv (304 quad tasks on 256 threads) ----
        ytask(tid >> 3, tid & 7);
        if (tid < 48) ytask(32 + (tid >> 3), tid & 7);
        __syncthreads();

        // ---- phase B: x-conv (4 outputs/thread) ----
        float sy[5][4];
#pragma unroll
        for (int c = 0; c < 5; ++c) {
            const float* yp = &yc[c * YCH + xrd];
            float v[10];
#pragma unroll
            for (int m = 0; m < 10; ++m) v[m] = yp[m];
#pragma unroll
            for (int o = 0; o < 4; ++o) {
                float sv = 0.f;
#pragma unroll
                for (int k = 0; k < 7; ++k) sv = fmaf(Wk[k], v[o + k], sv);
                sy[c][o] = sv;
            }
        }

        // ---- z scatter into two half2 pipes ----
#pragma unroll
        for (int c = 0; c < 5; ++c) {
            __half2 a2 = __floats2half2_rn(sy[c][0], sy[c][1]);
            __half2 b2 = __floats2half2_rn(sy[c][2], sy[c][3]);
#pragma unroll
            for (int j = 0; j < 7; ++j) {
                __half2 w2 = __float2half2_rn(Wk[6 - j]);
                azA[c][j] = __hfma2(w2, a2, azA[c][j]);
                azB[c][j] = __hfma2(w2, b2, azB[c][j]);
            }
        }

        if (i >= 6) {
#pragma unroll
            for (int pipe = 0; pipe < 2; ++pipe) {
                __half2 h0 = pipe ? azB[0][0] : azA[0][0];
                __half2 h1 = pipe ? azB[1][0] : azA[1][0];
                __half2 h2 = pipe ? azB[2][0] : azA[2][0];
                __half2 h3 = pipe ? azB[3][0] : azA[3][0];
                __half2 h4 = pipe ? azB[4][0] : azA[4][0];
                {
                    float mp = __low2float(h0), mt = __low2float(h1);
                    float ep2 = __low2float(h2), et2 = __low2float(h3), ept = __low2float(h4);
                    float mp2 = mp * mp, mt2 = mt * mt, mpt = mp * mt;
                    float num = fmaf(2.f, mpt, 1e-4f) * fmaf(2.f, ept - mpt, 9e-4f);
                    float den = (mp2 + mt2 + 1e-4f) * ((ep2 - mp2) + (et2 - mt2) + 9e-4f);
                    lsum += num * __builtin_amdgcn_rcpf(den);
                }
                {
                    float mp = __high2float(h0), mt = __high2float(h1);
                    float ep2 = __high2float(h2), et2 = __high2float(h3), ept = __high2float(h4);
                    float mp2 = mp * mp, mt2 = mt * mt, mpt = mp * mt;
                    float num = fmaf(2.f, mpt, 1e-4f) * fmaf(2.f, ept - mpt, 9e-4f);
                    float den = (mp2 + mt2 + 1e-4f) * ((ep2 - mp2) + (et2 - mt2) + 9e-4f);
                    lsum += num * __builtin_amdgcn_rcpf(den);
                }
            }
        }

        // ---- shift z pipes ----
#pragma unroll
        for (int c = 0; c < 5; ++c) {
#pragma unroll
            for (int j = 0; j < 6; ++j) { azA[c][j] = azA[c][j + 1]; azB[c][j] = azB[c][j + 1]; }
            azA[c][6] = hz; azB[c][6] = hz;
        }

        // ---- commit next slice (phase B writes sPT; y-conv reads done) ----
        if (hn) {
#pragma unroll
            for (int k = 0; k < 6; ++k)
                if (st[k]) sPT[tid + 256 * k] = make_float2(rp[k], rt[k]);
        }
        __syncthreads();
    }

    // ---- block reduction, one f64 atomic ----
#pragma unroll
    for (int off = 32; off > 0; off >>= 1) lsum += __shfl_down(lsum, off);
    if ((tid & 63) == 0) red[tid >> 6] = lsum;
    __syncthreads();
    if (tid == 0) atomicAdd(acc, (double)(red[0] + red[1] + red[2] + red[3]));
}

__global__ void ssim_finalize(const double* __restrict__ acc, float* __restrict__ out) {
    if (threadIdx.x == 0 && blockIdx.x == 0)
        out[0] = 1.f - (float)(acc[0] / NVOX_D);
}

extern "C" void kernel_launch(void* const* d_in, const int* in_sizes, int n_in,
                              void* d_out, int out_size, void* d_ws, size_t ws_size,
                              hipStream_t stream) {
    const float* P = (const float*)d_in[0];
    const float* T = (const float*)d_in[1];
    float* out = (float*)d_out;
    double* acc = (double*)d_ws;

    ssim_zero_acc<<<1, 64, 0, stream>>>(acc);
    ssim_main<<<4 * 8 * 5 * 5, 256, 0, stream>>>(P, T, acc);
    ssim_finalize<<<1, 64, 0, stream>>>(acc, out);
}

// Round 8
// 102.591 us; speedup vs baseline: 1.7387x; 1.5241x over previous
//
#include <hip/hip_runtime.h>
#include <hip/hip_fp16.h>

#define DIM   160
#define DIM2  25600
#define TY    32
#define TX    32
#define TZ    16
#define HY    38            // TY + 6
#define HX    38            // TX + 6
#define SS    51            // LDS row stride in dwords: 2*51 % 32 == 6 -> addr ≡ lane
#define NSL   22            // TZ + 6
#define NSITE (HY * HX)     // 1444
#define NVOX_D 16384000.0

#define W0 0.03663285f
#define W1 0.11128076f
#define W2 0.21674532f
#define W3 0.27068213f

__global__ void ssim_zero_acc(double* acc) {
    if (threadIdx.x == 0 && blockIdx.x == 0) acc[0] = 0.0;
}

__global__ __launch_bounds__(256, 3) void ssim_main(const float* __restrict__ P,
                                                    const float* __restrict__ T,
                                                    double* __restrict__ acc) {
    const float Wf[7] = {W0, W1, W2, W3, W2, W1, W0};
    const __half2 wh[7] = {__float2half2_rn(W0), __float2half2_rn(W1),
                           __float2half2_rn(W2), __float2half2_rn(W3),
                           __float2half2_rn(W2), __float2half2_rn(W1),
                           __float2half2_rn(W0)};

    __shared__ __half2 sIn[HY * SS];    // (p,t) packed, single buffer
    __shared__ __half2 ycMu[TY * SS];   // (yconv p, yconv t)
    __shared__ __half2 ycE2[TY * SS];   // (yconv p^2, yconv t^2)
    __shared__ float   ycPt[TY * SS];   // yconv p*t
    __shared__ float   red[4];

    const int tid = threadIdx.x;
    int bid = blockIdx.x;
    int b  = bid / 250;  int r  = bid - b * 250;   // 10 zc * 5 ty * 5 tx
    int zc = r / 25;     int r2 = r - zc * 25;
    int ty = r2 / 5;     int tx = r2 - ty * 5;

    const int base = b * (DIM * DIM * DIM);
    const int z0 = zc * TZ, y0 = ty * TY - 3, x0 = tx * TX - 3;

    // ---- hoisted staging sites (u = tid + 256k, k<6; 1444 = 5*256 + 164) ----
    int gofs[6], lofs[6];
    bool ld[6], st[6];
#pragma unroll
    for (int k = 0; k < 6; ++k) {
        int u = tid + 256 * k;
        st[k] = (u < NSITE);
        int y = u / HX, x = u - y * HX;
        int gy = y0 + y, gx = x0 + x;
        ld[k] = st[k] & ((unsigned)gy < (unsigned)DIM) & ((unsigned)gx < (unsigned)DIM);
        gofs[k] = gy * DIM + gx;
        lofs[k] = y * SS + x;
    }

    // ---- y-conv pair-task bases (t -> rows 2*(t/38), 2*(t/38)+1, col t%38) ----
    int yb[3];
#pragma unroll
    for (int q = 0; q < 3; ++q) {
        int t = tid + 256 * q; if (t > 607) t = 607;
        int yy = t / HX, x = t - yy * HX;
        yb[q] = (2 * yy) * SS + x;
    }

    // ---- x-conv: row cy = tid>>3 (32 rows), quad xq = tid&7 -> 4 voxels ----
    const int xrd = (tid >> 3) * SS + 4 * (tid & 7);

    const __half2 hz = __float2half2_rn(0.f);
    __half2 azMu[4][7], azE2[4][7], azPtA[7], azPtB[7];
#pragma unroll
    for (int o = 0; o < 4; ++o)
#pragma unroll
        for (int j = 0; j < 7; ++j) { azMu[o][j] = hz; azE2[o][j] = hz; }
#pragma unroll
    for (int j = 0; j < 7; ++j) { azPtA[j] = hz; azPtB[j] = hz; }

    float lsum = 0.f;

    // y-conv vertical pair: reads 8 packed taps, writes 2 rows x 3 arrays
    auto ytask = [&](int ybase) {
        __half2 mu0 = hz, mu1 = hz, e20 = hz, e21 = hz;
        float pt0 = 0.f, pt1 = 0.f;
#pragma unroll
        for (int k = 0; k < 8; ++k) {
            __half2 v  = sIn[ybase + k * SS];
            __half2 v2 = __hmul2(v, v);
            __half2 vs = __halves2half2(__high2half(v), __low2half(v));
            float ptf  = __low2float(__hmul2(v, vs));
            if (k < 7) {
                mu0 = __hfma2(wh[k], v, mu0);
                e20 = __hfma2(wh[k], v2, e20);
                pt0 = fmaf(Wf[k], ptf, pt0);
            }
            if (k >= 1) {
                mu1 = __hfma2(wh[k - 1], v, mu1);
                e21 = __hfma2(wh[k - 1], v2, e21);
                pt1 = fmaf(Wf[k - 1], ptf, pt1);
            }
        }
        ycMu[ybase] = mu0; ycMu[ybase + SS] = mu1;
        ycE2[ybase] = e20; ycE2[ybase + SS] = e21;
        ycPt[ybase] = pt0; ycPt[ybase + SS] = pt1;
    };

    // ---- prologue: stage slice zs = z0-3 ----
    {
        int zs = z0 - 3;
        bool zok = (unsigned)zs < (unsigned)DIM;
        const float* Pp = P + base + zs * DIM2;
        const float* Tp = T + base + zs * DIM2;
        float rp[6], rt[6];
#pragma unroll
        for (int k = 0; k < 6; ++k) {
            rp[k] = 0.f; rt[k] = 0.f;
            if (zok && ld[k]) { rp[k] = Pp[gofs[k]]; rt[k] = Tp[gofs[k]]; }
        }
#pragma unroll
        for (int k = 0; k < 6; ++k)
            if (st[k]) sIn[lofs[k]] = __floats2half2_rn(rp[k], rt[k]);
    }
    __syncthreads();

    for (int i = 0; i < NSL; ++i) {
        const bool hn = (i + 1 < NSL);
        float rp[6], rt[6];

        // ---- prefetch next slice into regs (hides HBM under y-conv) ----
        if (hn) {
            int zs = z0 + i - 2;
            bool zok = (unsigned)zs < (unsigned)DIM;
            const float* Pp = P + base + zs * DIM2;
            const float* Tp = T + base + zs * DIM2;
#pragma unroll
            for (int k = 0; k < 6; ++k) {
                rp[k] = 0.f; rt[k] = 0.f;
                if (zok && ld[k]) { rp[k] = Pp[gofs[k]]; rt[k] = Tp[gofs[k]]; }
            }
        }

        // ---- phase A: y-conv (608 pair tasks on 256 threads) ----
        ytask(yb[0]);
        ytask(yb[1]);
        if (tid < 96) ytask(yb[2]);
        __syncthreads();

        // ---- phase B: x-conv (4 outputs/thread, all b32 reads) ----
        __half2 muw[10], e2w[10]; float ptw[10];
#pragma unroll
        for (int m = 0; m < 10; ++m) {
            muw[m] = ycMu[xrd + m];
            e2w[m] = ycE2[xrd + m];
            ptw[m] = ycPt[xrd + m];
        }
        __half2 xmu[4], xe2[4]; float xpt[4];
#pragma unroll
        for (int o = 0; o < 4; ++o) {
            __half2 am = hz, ae = hz; float ap = 0.f;
#pragma unroll
            for (int k = 0; k < 7; ++k) {
                am = __hfma2(wh[k], muw[o + k], am);
                ae = __hfma2(wh[k], e2w[o + k], ae);
                ap = fmaf(Wf[k], ptw[o + k], ap);
            }
            xmu[o] = am; xe2[o] = ae; xpt[o] = ap;
        }

        // ---- z scatter ----
        __half2 ptA = __floats2half2_rn(xpt[0], xpt[1]);
        __half2 ptB = __floats2half2_rn(xpt[2], xpt[3]);
#pragma unroll
        for (int j = 0; j < 7; ++j) {
            __half2 w2 = wh[6 - j];
#pragma unroll
            for (int o = 0; o < 4; ++o) {
                azMu[o][j] = __hfma2(w2, xmu[o], azMu[o][j]);
                azE2[o][j] = __hfma2(w2, xe2[o], azE2[o][j]);
            }
            azPtA[j] = __hfma2(w2, ptA, azPtA[j]);
            azPtB[j] = __hfma2(w2, ptB, azPtB[j]);
        }

        // ---- SSIM on completed slot 0 ----
        if (i >= 6) {
            float eptv[4] = {__low2float(azPtA[0]), __high2float(azPtA[0]),
                             __low2float(azPtB[0]), __high2float(azPtB[0])};
#pragma unroll
            for (int o = 0; o < 4; ++o) {
                float mp = __low2float(azMu[o][0]), mt = __high2float(azMu[o][0]);
                float ep2 = __low2float(azE2[o][0]), et2 = __high2float(azE2[o][0]);
                float mp2 = mp * mp, mt2 = mt * mt, mpt = mp * mt;
                float num = fmaf(2.f, mpt, 1e-4f) * fmaf(2.f, eptv[o] - mpt, 9e-4f);
                float den = (mp2 + mt2 + 1e-4f) * ((ep2 - mp2) + (et2 - mt2) + 9e-4f);
                lsum += num * __builtin_amdgcn_rcpf(den);
            }
        }

        // ---- shift z pipes ----
#pragma unroll
        for (int j = 0; j < 6; ++j) {
#pragma unroll
            for (int o = 0; o < 4; ++o) {
                azMu[o][j] = azMu[o][j + 1];
                azE2[o][j] = azE2[o][j + 1];
            }
            azPtA[j] = azPtA[j + 1];
            azPtB[j] = azPtB[j + 1];
        }
#pragma unroll
        for (int o = 0; o < 4; ++o) { azMu[o][6] = hz; azE2[o][6] = hz; }
        azPtA[6] = hz; azPtB[6] = hz;

        // ---- commit next slice (b32 packed writes) ----
        if (hn) {
#pragma unroll
            for (int k = 0; k < 6; ++k)
                if (st[k]) sIn[lofs[k]] = __floats2half2_rn(rp[k], rt[k]);
        }
        __syncthreads();
    }

    // ---- block reduction, one f64 atomic ----
#pragma unroll
    for (int off = 32; off > 0; off >>= 1) lsum += __shfl_down(lsum, off);
    if ((tid & 63) == 0) red[tid >> 6] = lsum;
    __syncthreads();
    if (tid == 0) atomicAdd(acc, (double)(red[0] + red[1] + red[2] + red[3]));
}

__global__ void ssim_finalize(const double* __restrict__ acc, float* __restrict__ out) {
    if (threadIdx.x == 0 && blockIdx.x == 0)
        out[0] = 1.f - (float)(acc[0] / NVOX_D);
}

extern "C" void kernel_launch(void* const* d_in, const int* in_sizes, int n_in,
                              void* d_out, int out_size, void* d_ws, size_t ws_size,
                              hipStream_t stream) {
    const float* P = (const float*)d_in[0];
    const float* T = (const float*)d_in[1];
    float* out = (float*)d_out;
    double* acc = (double*)d_ws;

    ssim_zero_acc<<<1, 64, 0, stream>>>(acc);
    ssim_main<<<4 * 10 * 5 * 5, 256, 0, stream>>>(P, T, acc);
    ssim_finalize<<<1, 64, 0, stream>>>(acc, out);
}